// Round 4
// baseline (435.255 us; speedup 1.0000x reference)
//
#include <hip/hip_runtime.h>
#include <stdint.h>
#include <stddef.h>

#define HIDDEN 2048
#define INTER  5632
#define TOKENS 4096   // B*S = 2*2048
#define BK     32     // f16 K-tile (down GEMM)
#define BKI    64     // i8 K-tile (gateup GEMM) -- same 64B/row as f16 BK=32

typedef __attribute__((ext_vector_type(8))) _Float16 f16x8;
typedef __attribute__((ext_vector_type(4))) _Float16 f16x4;
typedef __attribute__((ext_vector_type(4))) float    f32x4;
typedef __attribute__((ext_vector_type(4))) int      i32x4;

// ---------------------------------------------------------------------------
// per-token dynamic i8 quantization of x: one block per token (2048 floats)
// ---------------------------------------------------------------------------
__global__ __launch_bounds__(256)
void quant_x(const float* __restrict__ x, int8_t* __restrict__ xq,
             float* __restrict__ xs) {
    const int t   = blockIdx.x;
    const int tid = threadIdx.x;
    const float4* row = (const float4*)(x + (size_t)t * HIDDEN);
    float4 v0 = row[tid * 2];
    float4 v1 = row[tid * 2 + 1];
    float m = fmaxf(fmaxf(fabsf(v0.x), fabsf(v0.y)), fmaxf(fabsf(v0.z), fabsf(v0.w)));
    m = fmaxf(m, fmaxf(fmaxf(fabsf(v1.x), fabsf(v1.y)), fmaxf(fabsf(v1.z), fabsf(v1.w))));
    #pragma unroll
    for (int off = 32; off; off >>= 1)
        m = fmaxf(m, __shfl_xor(m, off, 64));
    __shared__ float wmax[4];
    if ((tid & 63) == 0) wmax[tid >> 6] = m;
    __syncthreads();
    m = fmaxf(fmaxf(wmax[0], wmax[1]), fmaxf(wmax[2], wmax[3]));
    m = fmaxf(m, 1e-20f);
    if (tid == 0) xs[t] = m * (1.0f / 127.0f);
    const float inv = 127.0f / m;
    float vals[8] = {v0.x, v0.y, v0.z, v0.w, v1.x, v1.y, v1.z, v1.w};
    int b[8];
    #pragma unroll
    for (int i = 0; i < 8; ++i) b[i] = (int)rintf(vals[i] * inv);
    int lo = (b[0] & 255) | ((b[1] & 255) << 8) | ((b[2] & 255) << 16) | (b[3] << 24);
    int hi = (b[4] & 255) | ((b[5] & 255) << 8) | ((b[6] & 255) << 16) | (b[7] << 24);
    ((int2*)(xq + (size_t)t * HIDDEN))[tid] = make_int2(lo, hi);
}

// ---------------------------------------------------------------------------
// weight conversion: gate/up fp32 {-1,0,1} -> i8 exact; down fp32 -> f16 exact
// ---------------------------------------------------------------------------
__global__ void cvt_w(const float4* __restrict__ gw, const float4* __restrict__ uw,
                      const float4* __restrict__ dw,
                      int* __restrict__ go, int* __restrict__ uo,
                      f16x4* __restrict__ dno) {
    const int NW4 = INTER * HIDDEN / 4;   // 2,883,584
    int i = blockIdx.x * blockDim.x + threadIdx.x;
    const int stride = gridDim.x * blockDim.x;
    for (; i < 3 * NW4; i += stride) {
        if (i < 2 * NW4) {
            const bool is_g = i < NW4;
            const int j = is_g ? i : i - NW4;
            float4 f = is_g ? gw[j] : uw[j];
            int p = ((int)(signed char)(int)f.x & 255)
                  | (((int)(signed char)(int)f.y & 255) << 8)
                  | (((int)(signed char)(int)f.z & 255) << 16)
                  | (((int)(signed char)(int)f.w) << 24);
            if (is_g) go[j] = p; else uo[j] = p;
        } else {
            const int j = i - 2 * NW4;
            float4 f = dw[j];
            f16x4 o;
            o.x = (_Float16)f.x; o.y = (_Float16)f.y;
            o.z = (_Float16)f.z; o.w = (_Float16)f.w;
            dno[j] = o;
        }
    }
}

// ---------------------------------------------------------------------------
// GEMM1 fused (i8): H = silu(G*xs*gs) * (U*xs*us)  (fp16 out)
// 1D grid with GROUP_M=16 band swizzle for L2 locality.
// ---------------------------------------------------------------------------
__global__ __launch_bounds__(256, 2)
void gemm_gateup(const int8_t* __restrict__ Xq,
                 const int8_t* __restrict__ Wg,
                 const int8_t* __restrict__ Wu,
                 const float* __restrict__ xs,
                 const float* __restrict__ gs,
                 const float* __restrict__ us,
                 _Float16* __restrict__ Hm) {
    __shared__ int8_t As [128 * BKI];
    __shared__ int8_t Bgs[128 * BKI];
    __shared__ int8_t Bus[128 * BKI];

    // swizzle: bands of 16 m-tiles, n-major inside a band (44 n-tiles)
    const int pid   = blockIdx.x;          // 0..1407
    const int local = pid % (16 * 44);
    const int bm    = ((pid / (16 * 44)) * 16 + (local & 15)) * 128;
    const int bn    = (local >> 4) * 128;

    const int tid  = threadIdx.x;
    const int lane = tid & 63;
    const int wave = tid >> 6;
    const int wm   = (wave >> 1) * 64;
    const int wn   = (wave & 1) * 64;
    const int l15  = lane & 15;
    const int lq   = lane >> 4;

    const int f0 = tid,       f1 = tid + 256;
    const int row0 = f0 >> 2, row1 = f1 >> 2;
    const int sg0 = (f0 & 3) * 16, sg1 = (f1 & 3) * 16;

    const int8_t* gX0 = Xq + (size_t)(bm + row0) * HIDDEN + sg0;
    const int8_t* gX1 = Xq + (size_t)(bm + row1) * HIDDEN + sg1;
    const int8_t* gG0 = Wg + (size_t)(bn + row0) * HIDDEN + sg0;
    const int8_t* gG1 = Wg + (size_t)(bn + row1) * HIDDEN + sg1;
    const int8_t* gU0 = Wu + (size_t)(bn + row0) * HIDDEN + sg0;
    const int8_t* gU1 = Wu + (size_t)(bn + row1) * HIDDEN + sg1;

    i32x4 accg[4][4] = {};
    i32x4 accu[4][4] = {};

    for (int k0 = 0; k0 < HIDDEN; k0 += BKI) {
        __builtin_amdgcn_global_load_lds(
            (__attribute__((address_space(1))) void*)(gX0 + k0),
            (__attribute__((address_space(3))) void*)&As[f0 * 16], 16, 0, 0);
        __builtin_amdgcn_global_load_lds(
            (__attribute__((address_space(1))) void*)(gX1 + k0),
            (__attribute__((address_space(3))) void*)&As[f1 * 16], 16, 0, 0);
        __builtin_amdgcn_global_load_lds(
            (__attribute__((address_space(1))) void*)(gG0 + k0),
            (__attribute__((address_space(3))) void*)&Bgs[f0 * 16], 16, 0, 0);
        __builtin_amdgcn_global_load_lds(
            (__attribute__((address_space(1))) void*)(gG1 + k0),
            (__attribute__((address_space(3))) void*)&Bgs[f1 * 16], 16, 0, 0);
        __builtin_amdgcn_global_load_lds(
            (__attribute__((address_space(1))) void*)(gU0 + k0),
            (__attribute__((address_space(3))) void*)&Bus[f0 * 16], 16, 0, 0);
        __builtin_amdgcn_global_load_lds(
            (__attribute__((address_space(1))) void*)(gU1 + k0),
            (__attribute__((address_space(3))) void*)&Bus[f1 * 16], 16, 0, 0);
        __syncthreads();

        i32x4 a[4];
        #pragma unroll
        for (int im = 0; im < 4; ++im)
            a[im] = *(const i32x4*)&As[(wm + im * 16 + l15) * BKI + lq * 16];
        #pragma unroll
        for (int jn = 0; jn < 4; ++jn) {
            i32x4 bg = *(const i32x4*)&Bgs[(wn + jn * 16 + l15) * BKI + lq * 16];
            i32x4 bu = *(const i32x4*)&Bus[(wn + jn * 16 + l15) * BKI + lq * 16];
            #pragma unroll
            for (int im = 0; im < 4; ++im) {
                accg[im][jn] = __builtin_amdgcn_mfma_i32_16x16x64_i8(a[im], bg, accg[im][jn], 0, 0, 0);
                accu[im][jn] = __builtin_amdgcn_mfma_i32_16x16x64_i8(a[im], bu, accu[im][jn], 0, 0, 0);
            }
        }
        __syncthreads();
    }

    #pragma unroll
    for (int jn = 0; jn < 4; ++jn) {
        const int col = bn + wn + jn * 16 + l15;
        const float sg = gs[col];
        const float su = us[col];
        #pragma unroll
        for (int im = 0; im < 4; ++im) {
            const int rbase = bm + wm + im * 16 + lq * 4;
            #pragma unroll
            for (int r = 0; r < 4; ++r) {
                const int row = rbase + r;
                const float st = xs[row];
                float g = (float)accg[im][jn][r] * st * sg;
                float u = (float)accu[im][jn][r] * st * su;
                float h = (g / (1.0f + __expf(-g))) * u;
                Hm[(size_t)row * INTER + col] = (_Float16)h;
            }
        }
    }
}

// ---------------------------------------------------------------------------
// GEMM2 split-K=2: partial[seg] = H[:, segK] @ Wd[:, segK]^T   (fp16 partials)
// 1024 blocks -> 4/CU, 16 waves/CU. GROUP_M=16 swizzle, K-segment slowest.
// ---------------------------------------------------------------------------
__global__ __launch_bounds__(256, 4)
void gemm_down(const _Float16* __restrict__ Hm,
               const _Float16* __restrict__ Wd,
               _Float16* __restrict__ part) {
    __shared__ _Float16 As[128 * BK];
    __shared__ _Float16 Bs[128 * BK];

    const int pid = blockIdx.x;            // 0..1023
    const int seg = pid >> 9;              // 0..1  K-half
    const int s   = pid & 511;
    const int loc = s & 255;               // band = s>>8 (2 bands of 16m x 16n)
    const int bm  = ((s >> 8) * 16 + (loc & 15)) * 128;
    const int bn  = (loc >> 4) * 128;
    const int kbeg = seg * (INTER / 2);    // 2816

    const int tid  = threadIdx.x;
    const int lane = tid & 63;
    const int wave = tid >> 6;
    const int wm   = (wave >> 1) * 64;
    const int wn   = (wave & 1) * 64;
    const int l15  = lane & 15;
    const int lq   = lane >> 4;

    const int f0 = tid,       f1 = tid + 256;
    const int row0 = f0 >> 2, row1 = f1 >> 2;
    const int sg0 = (f0 & 3) * 8, sg1 = (f1 & 3) * 8;

    const _Float16* gA0 = Hm + (size_t)(bm + row0) * INTER + kbeg + sg0;
    const _Float16* gA1 = Hm + (size_t)(bm + row1) * INTER + kbeg + sg1;
    const _Float16* gB0 = Wd + (size_t)(bn + row0) * INTER + kbeg + sg0;
    const _Float16* gB1 = Wd + (size_t)(bn + row1) * INTER + kbeg + sg1;

    f32x4 acc[4][4] = {};

    for (int k0 = 0; k0 < INTER / 2; k0 += BK) {
        __builtin_amdgcn_global_load_lds(
            (__attribute__((address_space(1))) void*)(gA0 + k0),
            (__attribute__((address_space(3))) void*)&As[f0 * 8], 16, 0, 0);
        __builtin_amdgcn_global_load_lds(
            (__attribute__((address_space(1))) void*)(gA1 + k0),
            (__attribute__((address_space(3))) void*)&As[f1 * 8], 16, 0, 0);
        __builtin_amdgcn_global_load_lds(
            (__attribute__((address_space(1))) void*)(gB0 + k0),
            (__attribute__((address_space(3))) void*)&Bs[f0 * 8], 16, 0, 0);
        __builtin_amdgcn_global_load_lds(
            (__attribute__((address_space(1))) void*)(gB1 + k0),
            (__attribute__((address_space(3))) void*)&Bs[f1 * 8], 16, 0, 0);
        __syncthreads();

        f16x8 a[4];
        #pragma unroll
        for (int im = 0; im < 4; ++im)
            a[im] = *(const f16x8*)&As[(wm + im * 16 + l15) * BK + lq * 8];
        #pragma unroll
        for (int jn = 0; jn < 4; ++jn) {
            f16x8 b = *(const f16x8*)&Bs[(wn + jn * 16 + l15) * BK + lq * 8];
            #pragma unroll
            for (int im = 0; im < 4; ++im)
                acc[im][jn] = __builtin_amdgcn_mfma_f32_16x16x32_f16(a[im], b, acc[im][jn], 0, 0, 0);
        }
        __syncthreads();
    }

    _Float16* po = part + (size_t)seg * TOKENS * HIDDEN;
    #pragma unroll
    for (int jn = 0; jn < 4; ++jn) {
        const int col = bn + wn + jn * 16 + l15;
        #pragma unroll
        for (int im = 0; im < 4; ++im) {
            const int rbase = bm + wm + im * 16 + lq * 4;
            #pragma unroll
            for (int r = 0; r < 4; ++r)
                po[(size_t)(rbase + r) * HIDDEN + col] = (_Float16)acc[im][jn][r];
        }
    }
}

// ---------------------------------------------------------------------------
// reduce: out = (p0 + p1) * down_s
// ---------------------------------------------------------------------------
__global__ void reduce_down(const f16x4* __restrict__ p,
                            const float* __restrict__ dsc,
                            float4* __restrict__ out) {
    const int N4 = TOKENS * HIDDEN / 4;    // 2,097,152
    int i = blockIdx.x * blockDim.x + threadIdx.x;
    const int stride = gridDim.x * blockDim.x;
    for (; i < N4; i += stride) {
        f16x4 a = p[i];
        f16x4 b = p[i + N4];
        const int c = (i * 4) & (HIDDEN - 1);
        float4 o;
        o.x = ((float)a.x + (float)b.x) * dsc[c];
        o.y = ((float)a.y + (float)b.y) * dsc[c + 1];
        o.z = ((float)a.z + (float)b.z) * dsc[c + 2];
        o.w = ((float)a.w + (float)b.w) * dsc[c + 3];
        out[i] = o;
    }
}

// ---------------------------------------------------------------------------
// launch
// ---------------------------------------------------------------------------
extern "C" void kernel_launch(void* const* d_in, const int* in_sizes, int n_in,
                              void* d_out, int out_size, void* d_ws, size_t ws_size,
                              hipStream_t stream) {
    const float* x   = (const float*)d_in[0];
    const float* gw  = (const float*)d_in[1];
    const float* uw  = (const float*)d_in[2];
    const float* dw  = (const float*)d_in[3];
    const float* gsc = (const float*)d_in[4];
    const float* usc = (const float*)d_in[5];
    const float* dsc = (const float*)d_in[6];
    float* out = (float*)d_out;

    // workspace layout (partials alias the gateup-only inputs, dead by then):
    //   Wdh  f16 @          0 : 23,068,672
    //   Hm   f16 @ 23,068,672 : 46,137,344   (ends  69,206,016)
    //   Xq   i8  @ 69,206,016 :  8,388,608   (ends  77,594,624)  } aliased by
    //   Wg8  i8  @ 77,594,624 : 11,534,336   (ends  89,128,960)  } part f16
    //   Wu8  i8  @ 89,128,960 : 11,534,336   (ends 100,663,296)  } 33,554,432
    //   part f16 @ 69,206,016 : 33,554,432   (ends 102,760,448)
    //   xs   f32 @102,760,448 :     16,384   (ends 102,776,832)  total ~102.8MB
    char* ws = (char*)d_ws;
    _Float16* Wdh  = (_Float16*)(ws);
    _Float16* Hm   = (_Float16*)(ws + 23068672ull);
    int8_t*   Xq   = (int8_t*)(ws + 69206016ull);
    int8_t*   Wg8  = (int8_t*)(ws + 77594624ull);
    int8_t*   Wu8  = (int8_t*)(ws + 89128960ull);
    _Float16* part = (_Float16*)(ws + 69206016ull);   // alias (dead region)
    float*    xs   = (float*)(ws + 102760448ull);

    quant_x<<<TOKENS, 256, 0, stream>>>(x, Xq, xs);
    cvt_w<<<2048, 256, 0, stream>>>((const float4*)gw, (const float4*)uw,
                                    (const float4*)dw,
                                    (int*)Wg8, (int*)Wu8, (f16x4*)Wdh);

    gemm_gateup<<<(INTER / 128) * (TOKENS / 128), 256, 0, stream>>>(
        Xq, Wg8, Wu8, xs, gsc, usc, Hm);
    gemm_down<<<2 * (HIDDEN / 128) * (TOKENS / 128), 256, 0, stream>>>(
        Hm, Wdh, part);
    reduce_down<<<2048, 256, 0, stream>>>((const f16x4*)part, dsc, (float4*)out);
}

// Round 5
// 417.288 us; speedup vs baseline: 1.0431x; 1.0431x over previous
//
#include <hip/hip_runtime.h>
#include <stdint.h>
#include <stddef.h>

#define HIDDEN 2048
#define INTER  5632
#define TOKENS 4096   // B*S = 2*2048
#define BK     32     // f16 K-tile (down GEMM)  -> 64B rows
#define BKI    64     // i8 K-tile (gateup GEMM) -> 64B rows

typedef __attribute__((ext_vector_type(8))) _Float16 f16x8;
typedef __attribute__((ext_vector_type(4))) _Float16 f16x4;
typedef __attribute__((ext_vector_type(4))) float    f32x4;
typedef __attribute__((ext_vector_type(4))) int      i32x4;

// Within-row LDS swizzle: row = 4 x 16B segments; segment q of row r lives at
// slot r*4 + ((q + (r>>1)) & 3).  l15-runs (fixed q, consecutive rows) then
// cover 8 distinct bank-quads per 8 lanes (even rows -> quads q..q+3, odd ->
// 4+q..4+q+3) => conflict-free reads. Permutation stays inside each row's 64B
// so staging threads of one row still cover one cacheline (coalescing kept).
__device__ __forceinline__ int swz_slot(int row, int q) {
    return row * 4 + ((q + (row >> 1)) & 3);
}

// ---------------------------------------------------------------------------
// per-token dynamic i8 quantization of x
// ---------------------------------------------------------------------------
__global__ __launch_bounds__(256)
void quant_x(const float* __restrict__ x, int8_t* __restrict__ xq,
             float* __restrict__ xs) {
    const int t   = blockIdx.x;
    const int tid = threadIdx.x;
    const float4* row = (const float4*)(x + (size_t)t * HIDDEN);
    float4 v0 = row[tid * 2];
    float4 v1 = row[tid * 2 + 1];
    float m = fmaxf(fmaxf(fabsf(v0.x), fabsf(v0.y)), fmaxf(fabsf(v0.z), fabsf(v0.w)));
    m = fmaxf(m, fmaxf(fmaxf(fabsf(v1.x), fabsf(v1.y)), fmaxf(fabsf(v1.z), fabsf(v1.w))));
    #pragma unroll
    for (int off = 32; off; off >>= 1)
        m = fmaxf(m, __shfl_xor(m, off, 64));
    __shared__ float wmax[4];
    if ((tid & 63) == 0) wmax[tid >> 6] = m;
    __syncthreads();
    m = fmaxf(fmaxf(wmax[0], wmax[1]), fmaxf(wmax[2], wmax[3]));
    m = fmaxf(m, 1e-20f);
    if (tid == 0) xs[t] = m * (1.0f / 127.0f);
    const float inv = 127.0f / m;
    float vals[8] = {v0.x, v0.y, v0.z, v0.w, v1.x, v1.y, v1.z, v1.w};
    int b[8];
    #pragma unroll
    for (int i = 0; i < 8; ++i) b[i] = (int)rintf(vals[i] * inv);
    int lo = (b[0] & 255) | ((b[1] & 255) << 8) | ((b[2] & 255) << 16) | (b[3] << 24);
    int hi = (b[4] & 255) | ((b[5] & 255) << 8) | ((b[6] & 255) << 16) | (b[7] << 24);
    ((int2*)(xq + (size_t)t * HIDDEN))[tid] = make_int2(lo, hi);
}

// ---------------------------------------------------------------------------
// weight conversion: gate/up fp32 {-1,0,1} -> i8 exact; down fp32 -> f16 exact
// ---------------------------------------------------------------------------
__global__ void cvt_w(const float4* __restrict__ gw, const float4* __restrict__ uw,
                      const float4* __restrict__ dw,
                      int* __restrict__ go, int* __restrict__ uo,
                      f16x4* __restrict__ dno) {
    const int NW4 = INTER * HIDDEN / 4;
    int i = blockIdx.x * blockDim.x + threadIdx.x;
    const int stride = gridDim.x * blockDim.x;
    for (; i < 3 * NW4; i += stride) {
        if (i < 2 * NW4) {
            const bool is_g = i < NW4;
            const int j = is_g ? i : i - NW4;
            float4 f = is_g ? gw[j] : uw[j];
            int p = ((int)(signed char)(int)f.x & 255)
                  | (((int)(signed char)(int)f.y & 255) << 8)
                  | (((int)(signed char)(int)f.z & 255) << 16)
                  | (((int)(signed char)(int)f.w) << 24);
            if (is_g) go[j] = p; else uo[j] = p;
        } else {
            const int j = i - 2 * NW4;
            float4 f = dw[j];
            f16x4 o;
            o.x = (_Float16)f.x; o.y = (_Float16)f.y;
            o.z = (_Float16)f.z; o.w = (_Float16)f.w;
            dno[j] = o;
        }
    }
}

// ---------------------------------------------------------------------------
// GEMM1 fused (i8): H = silu(G*xs*gs) * (U*xs*us)  (fp16 out)
// Band-swizzled grid, swizzled LDS.
// ---------------------------------------------------------------------------
__global__ __launch_bounds__(256, 2)
void gemm_gateup(const int8_t* __restrict__ Xq,
                 const int8_t* __restrict__ Wg,
                 const int8_t* __restrict__ Wu,
                 const float* __restrict__ xs,
                 const float* __restrict__ gs,
                 const float* __restrict__ us,
                 _Float16* __restrict__ Hm) {
    __shared__ int8_t As [128 * BKI];
    __shared__ int8_t Bgs[128 * BKI];
    __shared__ int8_t Bus[128 * BKI];

    const int pid   = blockIdx.x;          // 0..1407
    const int local = pid % (16 * 44);
    const int bm    = ((pid / (16 * 44)) * 16 + (local & 15)) * 128;
    const int bn    = (local >> 4) * 128;

    const int tid  = threadIdx.x;
    const int lane = tid & 63;
    const int wave = tid >> 6;
    const int wm   = (wave >> 1) * 64;
    const int wn   = (wave & 1) * 64;
    const int l15  = lane & 15;
    const int lq   = lane >> 4;

    // staging: thread owns LDS slots f0/f1 (linear); fetches the PERMUTED
    // global segment q = ((f&3) - (row>>1)) & 3 of its row.
    const int f0 = tid,       f1 = tid + 256;
    const int row0 = f0 >> 2, row1 = f1 >> 2;
    const int sg0 = (((f0 & 3) - (row0 >> 1)) & 3) * 16;   // i8 elements
    const int sg1 = (((f1 & 3) - (row1 >> 1)) & 3) * 16;

    const int8_t* gX0 = Xq + (size_t)(bm + row0) * HIDDEN + sg0;
    const int8_t* gX1 = Xq + (size_t)(bm + row1) * HIDDEN + sg1;
    const int8_t* gG0 = Wg + (size_t)(bn + row0) * HIDDEN + sg0;
    const int8_t* gG1 = Wg + (size_t)(bn + row1) * HIDDEN + sg1;
    const int8_t* gU0 = Wu + (size_t)(bn + row0) * HIDDEN + sg0;
    const int8_t* gU1 = Wu + (size_t)(bn + row1) * HIDDEN + sg1;

    i32x4 accg[4][4] = {};
    i32x4 accu[4][4] = {};

    for (int k0 = 0; k0 < HIDDEN; k0 += BKI) {
        __builtin_amdgcn_global_load_lds(
            (__attribute__((address_space(1))) void*)(gX0 + k0),
            (__attribute__((address_space(3))) void*)&As[f0 * 16], 16, 0, 0);
        __builtin_amdgcn_global_load_lds(
            (__attribute__((address_space(1))) void*)(gX1 + k0),
            (__attribute__((address_space(3))) void*)&As[f1 * 16], 16, 0, 0);
        __builtin_amdgcn_global_load_lds(
            (__attribute__((address_space(1))) void*)(gG0 + k0),
            (__attribute__((address_space(3))) void*)&Bgs[f0 * 16], 16, 0, 0);
        __builtin_amdgcn_global_load_lds(
            (__attribute__((address_space(1))) void*)(gG1 + k0),
            (__attribute__((address_space(3))) void*)&Bgs[f1 * 16], 16, 0, 0);
        __builtin_amdgcn_global_load_lds(
            (__attribute__((address_space(1))) void*)(gU0 + k0),
            (__attribute__((address_space(3))) void*)&Bus[f0 * 16], 16, 0, 0);
        __builtin_amdgcn_global_load_lds(
            (__attribute__((address_space(1))) void*)(gU1 + k0),
            (__attribute__((address_space(3))) void*)&Bus[f1 * 16], 16, 0, 0);
        __syncthreads();

        i32x4 a[4];
        #pragma unroll
        for (int im = 0; im < 4; ++im) {
            const int r = wm + im * 16 + l15;
            a[im] = *(const i32x4*)&As[swz_slot(r, lq) * 16];
        }
        #pragma unroll
        for (int jn = 0; jn < 4; ++jn) {
            const int r = wn + jn * 16 + l15;
            i32x4 bg = *(const i32x4*)&Bgs[swz_slot(r, lq) * 16];
            i32x4 bu = *(const i32x4*)&Bus[swz_slot(r, lq) * 16];
            #pragma unroll
            for (int im = 0; im < 4; ++im) {
                accg[im][jn] = __builtin_amdgcn_mfma_i32_16x16x64_i8(a[im], bg, accg[im][jn], 0, 0, 0);
                accu[im][jn] = __builtin_amdgcn_mfma_i32_16x16x64_i8(a[im], bu, accu[im][jn], 0, 0, 0);
            }
        }
        __syncthreads();
    }

    #pragma unroll
    for (int jn = 0; jn < 4; ++jn) {
        const int col = bn + wn + jn * 16 + l15;
        const float sg = gs[col];
        const float su = us[col];
        #pragma unroll
        for (int im = 0; im < 4; ++im) {
            const int rbase = bm + wm + im * 16 + lq * 4;
            #pragma unroll
            for (int r = 0; r < 4; ++r) {
                const int row = rbase + r;
                const float st = xs[row];
                float g = (float)accg[im][jn][r] * st * sg;
                float u = (float)accu[im][jn][r] * st * su;
                float h = (g / (1.0f + __expf(-g))) * u;
                Hm[(size_t)row * INTER + col] = (_Float16)h;
            }
        }
    }
}

// ---------------------------------------------------------------------------
// GEMM2 (fp16): out = (H @ Wd^T) * down_s  (fp32 out). No split-K (R4 showed
// occupancy was not the limiter). Band-swizzled grid, swizzled LDS.
// ---------------------------------------------------------------------------
__global__ __launch_bounds__(256, 2)
void gemm_down(const _Float16* __restrict__ Hm,
               const _Float16* __restrict__ Wd,
               const float* __restrict__ dsc,
               float* __restrict__ out) {
    __shared__ _Float16 As[128 * BK];
    __shared__ _Float16 Bs[128 * BK];

    const int pid = blockIdx.x;            // 0..511
    const int loc = pid & 255;             // band = pid>>8 (2 bands 16m x 16n)
    const int bm  = ((pid >> 8) * 16 + (loc & 15)) * 128;
    const int bn  = (loc >> 4) * 128;

    const int tid  = threadIdx.x;
    const int lane = tid & 63;
    const int wave = tid >> 6;
    const int wm   = (wave >> 1) * 64;
    const int wn   = (wave & 1) * 64;
    const int l15  = lane & 15;
    const int lq   = lane >> 4;

    const int f0 = tid,       f1 = tid + 256;
    const int row0 = f0 >> 2, row1 = f1 >> 2;
    const int sg0 = (((f0 & 3) - (row0 >> 1)) & 3) * 8;    // f16 elements
    const int sg1 = (((f1 & 3) - (row1 >> 1)) & 3) * 8;

    const _Float16* gA0 = Hm + (size_t)(bm + row0) * INTER + sg0;
    const _Float16* gA1 = Hm + (size_t)(bm + row1) * INTER + sg1;
    const _Float16* gB0 = Wd + (size_t)(bn + row0) * INTER + sg0;
    const _Float16* gB1 = Wd + (size_t)(bn + row1) * INTER + sg1;

    f32x4 acc[4][4] = {};

    for (int k0 = 0; k0 < INTER; k0 += BK) {
        __builtin_amdgcn_global_load_lds(
            (__attribute__((address_space(1))) void*)(gA0 + k0),
            (__attribute__((address_space(3))) void*)&As[f0 * 8], 16, 0, 0);
        __builtin_amdgcn_global_load_lds(
            (__attribute__((address_space(1))) void*)(gA1 + k0),
            (__attribute__((address_space(3))) void*)&As[f1 * 8], 16, 0, 0);
        __builtin_amdgcn_global_load_lds(
            (__attribute__((address_space(1))) void*)(gB0 + k0),
            (__attribute__((address_space(3))) void*)&Bs[f0 * 8], 16, 0, 0);
        __builtin_amdgcn_global_load_lds(
            (__attribute__((address_space(1))) void*)(gB1 + k0),
            (__attribute__((address_space(3))) void*)&Bs[f1 * 8], 16, 0, 0);
        __syncthreads();

        f16x8 a[4];
        #pragma unroll
        for (int im = 0; im < 4; ++im) {
            const int r = wm + im * 16 + l15;
            a[im] = *(const f16x8*)&As[swz_slot(r, lq) * 8];
        }
        #pragma unroll
        for (int jn = 0; jn < 4; ++jn) {
            const int r = wn + jn * 16 + l15;
            f16x8 b = *(const f16x8*)&Bs[swz_slot(r, lq) * 8];
            #pragma unroll
            for (int im = 0; im < 4; ++im)
                acc[im][jn] = __builtin_amdgcn_mfma_f32_16x16x32_f16(a[im], b, acc[im][jn], 0, 0, 0);
        }
        __syncthreads();
    }

    #pragma unroll
    for (int jn = 0; jn < 4; ++jn) {
        const int col = bn + wn + jn * 16 + l15;
        const float sd = dsc[col];
        #pragma unroll
        for (int im = 0; im < 4; ++im) {
            const int rbase = bm + wm + im * 16 + lq * 4;
            #pragma unroll
            for (int r = 0; r < 4; ++r)
                out[(size_t)(rbase + r) * HIDDEN + col] = acc[im][jn][r] * sd;
        }
    }
}

// ---------------------------------------------------------------------------
// launch
// ---------------------------------------------------------------------------
extern "C" void kernel_launch(void* const* d_in, const int* in_sizes, int n_in,
                              void* d_out, int out_size, void* d_ws, size_t ws_size,
                              hipStream_t stream) {
    const float* x   = (const float*)d_in[0];
    const float* gw  = (const float*)d_in[1];
    const float* uw  = (const float*)d_in[2];
    const float* dw  = (const float*)d_in[3];
    const float* gsc = (const float*)d_in[4];
    const float* usc = (const float*)d_in[5];
    const float* dsc = (const float*)d_in[6];
    float* out = (float*)d_out;

    // workspace layout (R3):
    //   Xq  i8  @          0 :  8,388,608
    //   Wg8 i8  @  8,388,608 : 11,534,336
    //   Wu8 i8  @ 19,922,944 : 11,534,336
    //   Wdh f16 @ 31,457,280 : 23,068,672
    //   Hm  f16 @ 54,525,952 : 46,137,344
    //   xs  f32 @100,663,296 :     16,384
    char* ws = (char*)d_ws;
    int8_t*   Xq  = (int8_t*)(ws);
    int8_t*   Wg8 = (int8_t*)(ws + 8388608ull);
    int8_t*   Wu8 = (int8_t*)(ws + 19922944ull);
    _Float16* Wdh = (_Float16*)(ws + 31457280ull);
    _Float16* Hm  = (_Float16*)(ws + 54525952ull);
    float*    xs  = (float*)(ws + 100663296ull);

    quant_x<<<TOKENS, 256, 0, stream>>>(x, Xq, xs);
    cvt_w<<<2048, 256, 0, stream>>>((const float4*)gw, (const float4*)uw,
                                    (const float4*)dw,
                                    (int*)Wg8, (int*)Wu8, (f16x4*)Wdh);

    gemm_gateup<<<(INTER / 128) * (TOKENS / 128), 256, 0, stream>>>(
        Xq, Wg8, Wu8, xs, gsc, usc, Hm);
    gemm_down<<<(HIDDEN / 128) * (TOKENS / 128), 256, 0, stream>>>(
        Hm, Wdh, dsc, out);
}

// Round 6
// 388.432 us; speedup vs baseline: 1.1205x; 1.0743x over previous
//
#include <hip/hip_runtime.h>
#include <stdint.h>
#include <stddef.h>

#define HIDDEN 2048
#define INTER  5632
#define TOKENS 4096   // B*S = 2*2048
#define BK     64     // f16 K-tile (down GEMM)  -> 128B rows, 88 iters
#define BKI    128    // i8 K-tile (gateup GEMM) -> 128B rows, 16 iters

typedef __attribute__((ext_vector_type(8))) _Float16 f16x8;
typedef __attribute__((ext_vector_type(4))) _Float16 f16x4;
typedef __attribute__((ext_vector_type(4))) float    f32x4;
typedef __attribute__((ext_vector_type(4))) int      i32x4;

// 128B-row LDS swizzle: row = 8 x 16B segments; global segment q of row r
// lives at slot r*8 + ((q + (r>>1)) & 7). Fixed-q reads across 16 consecutive
// rows hit each bank-quad exactly 2x (2-way = free, m136). Staging fetches the
// permuted segment so LDS slots stay linear (global_load_lds constraint);
// permutation stays within the row's two 64B lines -> coalescing preserved.
__device__ __forceinline__ int swz8(int row, int q) {
    return row * 8 + ((q + (row >> 1)) & 7);
}

// ---------------------------------------------------------------------------
// fused prepass: blocks [0,TOKENS) quantize x per-token to i8;
// blocks [TOKENS, TOKENS+2048) grid-stride convert weights (gate/up->i8,
// down->f16)
// ---------------------------------------------------------------------------
__global__ __launch_bounds__(256)
void prepass(const float* __restrict__ x,
             const float4* __restrict__ gw, const float4* __restrict__ uw,
             const float4* __restrict__ dw,
             int8_t* __restrict__ xq, float* __restrict__ xs,
             int* __restrict__ go, int* __restrict__ uo,
             f16x4* __restrict__ dno) {
    const int tid = threadIdx.x;
    if (blockIdx.x < TOKENS) {
        const int t = blockIdx.x;
        const float4* row = (const float4*)(x + (size_t)t * HIDDEN);
        float4 v0 = row[tid * 2];
        float4 v1 = row[tid * 2 + 1];
        float m = fmaxf(fmaxf(fabsf(v0.x), fabsf(v0.y)), fmaxf(fabsf(v0.z), fabsf(v0.w)));
        m = fmaxf(m, fmaxf(fmaxf(fabsf(v1.x), fabsf(v1.y)), fmaxf(fabsf(v1.z), fabsf(v1.w))));
        #pragma unroll
        for (int off = 32; off; off >>= 1)
            m = fmaxf(m, __shfl_xor(m, off, 64));
        __shared__ float wmax[4];
        if ((tid & 63) == 0) wmax[tid >> 6] = m;
        __syncthreads();
        m = fmaxf(fmaxf(wmax[0], wmax[1]), fmaxf(wmax[2], wmax[3]));
        m = fmaxf(m, 1e-20f);
        if (tid == 0) xs[t] = m * (1.0f / 127.0f);
        const float inv = 127.0f / m;
        float vals[8] = {v0.x, v0.y, v0.z, v0.w, v1.x, v1.y, v1.z, v1.w};
        int b[8];
        #pragma unroll
        for (int i = 0; i < 8; ++i) b[i] = (int)rintf(vals[i] * inv);
        int lo = (b[0] & 255) | ((b[1] & 255) << 8) | ((b[2] & 255) << 16) | (b[3] << 24);
        int hi = (b[4] & 255) | ((b[5] & 255) << 8) | ((b[6] & 255) << 16) | (b[7] << 24);
        ((int2*)(xq + (size_t)t * HIDDEN))[tid] = make_int2(lo, hi);
        return;
    }
    const int NW4 = INTER * HIDDEN / 4;
    int i = (blockIdx.x - TOKENS) * blockDim.x + tid;
    const int stride = 2048 * blockDim.x;
    for (; i < 3 * NW4; i += stride) {
        if (i < 2 * NW4) {
            const bool is_g = i < NW4;
            const int j = is_g ? i : i - NW4;
            float4 f = is_g ? gw[j] : uw[j];
            int p = ((int)(signed char)(int)f.x & 255)
                  | (((int)(signed char)(int)f.y & 255) << 8)
                  | (((int)(signed char)(int)f.z & 255) << 16)
                  | (((int)(signed char)(int)f.w) << 24);
            if (is_g) go[j] = p; else uo[j] = p;
        } else {
            const int j = i - 2 * NW4;
            float4 f = dw[j];
            f16x4 o;
            o.x = (_Float16)f.x; o.y = (_Float16)f.y;
            o.z = (_Float16)f.z; o.w = (_Float16)f.w;
            dno[j] = o;
        }
    }
}

// ---------------------------------------------------------------------------
// GEMM1 fused (i8): H = silu(G*xs*gs) * (U*xs*us)  (fp16 out)
// 128x128 tile, BKI=128 (16 K-iters), LDS 48KB, band-swizzled grid.
// ---------------------------------------------------------------------------
__global__ __launch_bounds__(256, 2)
void gemm_gateup(const int8_t* __restrict__ Xq,
                 const int8_t* __restrict__ Wg,
                 const int8_t* __restrict__ Wu,
                 const float* __restrict__ xs,
                 const float* __restrict__ gs,
                 const float* __restrict__ us,
                 _Float16* __restrict__ Hm) {
    __shared__ int8_t As [128 * BKI];
    __shared__ int8_t Bgs[128 * BKI];
    __shared__ int8_t Bus[128 * BKI];

    const int pid   = blockIdx.x;          // 0..1407
    const int local = pid % (16 * 44);
    const int bm    = ((pid / (16 * 44)) * 16 + (local & 15)) * 128;
    const int bn    = (local >> 4) * 128;

    const int tid  = threadIdx.x;
    const int lane = tid & 63;
    const int wave = tid >> 6;
    const int wm   = (wave >> 1) * 64;
    const int wn   = (wave & 1) * 64;
    const int l15  = lane & 15;
    const int lq   = lane >> 4;

    // staging: 1024 16B-slots/tile, 256 threads x 4. slot f -> row f>>3,
    // fetches permuted global segment ((f&7) - (row>>1)) & 7.
    int rowA[4], sgA[4];
    #pragma unroll
    for (int j = 0; j < 4; ++j) {
        const int f = tid + 256 * j;
        rowA[j] = f >> 3;
        sgA[j]  = (((f & 7) - (rowA[j] >> 1)) & 7) * 16;
    }

    i32x4 accg[4][4] = {};
    i32x4 accu[4][4] = {};

    for (int k0 = 0; k0 < HIDDEN; k0 += BKI) {
        #pragma unroll
        for (int j = 0; j < 4; ++j) {
            const int f = tid + 256 * j;
            const int8_t* pX = Xq + (size_t)(bm + rowA[j]) * HIDDEN + k0 + sgA[j];
            const int8_t* pG = Wg + (size_t)(bn + rowA[j]) * HIDDEN + k0 + sgA[j];
            const int8_t* pU = Wu + (size_t)(bn + rowA[j]) * HIDDEN + k0 + sgA[j];
            __builtin_amdgcn_global_load_lds(
                (__attribute__((address_space(1))) void*)pX,
                (__attribute__((address_space(3))) void*)&As[f * 16], 16, 0, 0);
            __builtin_amdgcn_global_load_lds(
                (__attribute__((address_space(1))) void*)pG,
                (__attribute__((address_space(3))) void*)&Bgs[f * 16], 16, 0, 0);
            __builtin_amdgcn_global_load_lds(
                (__attribute__((address_space(1))) void*)pU,
                (__attribute__((address_space(3))) void*)&Bus[f * 16], 16, 0, 0);
        }
        __syncthreads();

        #pragma unroll
        for (int ks = 0; ks < 2; ++ks) {
            const int q = ks * 4 + lq;     // segment for this MFMA k-step
            i32x4 a[4];
            #pragma unroll
            for (int im = 0; im < 4; ++im)
                a[im] = *(const i32x4*)&As[swz8(wm + im * 16 + l15, q) * 16];
            #pragma unroll
            for (int jn = 0; jn < 4; ++jn) {
                i32x4 bg = *(const i32x4*)&Bgs[swz8(wn + jn * 16 + l15, q) * 16];
                i32x4 bu = *(const i32x4*)&Bus[swz8(wn + jn * 16 + l15, q) * 16];
                #pragma unroll
                for (int im = 0; im < 4; ++im) {
                    accg[im][jn] = __builtin_amdgcn_mfma_i32_16x16x64_i8(a[im], bg, accg[im][jn], 0, 0, 0);
                    accu[im][jn] = __builtin_amdgcn_mfma_i32_16x16x64_i8(a[im], bu, accu[im][jn], 0, 0, 0);
                }
            }
        }
        __syncthreads();
    }

    #pragma unroll
    for (int jn = 0; jn < 4; ++jn) {
        const int col = bn + wn + jn * 16 + l15;
        const float sg = gs[col];
        const float su = us[col];
        #pragma unroll
        for (int im = 0; im < 4; ++im) {
            const int rbase = bm + wm + im * 16 + lq * 4;
            #pragma unroll
            for (int r = 0; r < 4; ++r) {
                const int row = rbase + r;
                const float st = xs[row];
                float g = (float)accg[im][jn][r] * st * sg;
                float u = (float)accu[im][jn][r] * st * su;
                float h = (g / (1.0f + __expf(-g))) * u;
                Hm[(size_t)row * INTER + col] = (_Float16)h;
            }
        }
    }
}

// ---------------------------------------------------------------------------
// GEMM2 (fp16): out = (H @ Wd^T) * down_s  (fp32 out)
// 128x128 tile, BK=64 (88 K-iters), LDS 32KB, band-swizzled grid.
// ---------------------------------------------------------------------------
__global__ __launch_bounds__(256, 2)
void gemm_down(const _Float16* __restrict__ Hm,
               const _Float16* __restrict__ Wd,
               const float* __restrict__ dsc,
               float* __restrict__ out) {
    __shared__ _Float16 As[128 * BK];
    __shared__ _Float16 Bs[128 * BK];

    const int pid = blockIdx.x;            // 0..511
    const int loc = pid & 255;
    const int bm  = ((pid >> 8) * 16 + (loc & 15)) * 128;
    const int bn  = (loc >> 4) * 128;

    const int tid  = threadIdx.x;
    const int lane = tid & 63;
    const int wave = tid >> 6;
    const int wm   = (wave >> 1) * 64;
    const int wn   = (wave & 1) * 64;
    const int l15  = lane & 15;
    const int lq   = lane >> 4;

    int rowA[4], sgA[4];
    #pragma unroll
    for (int j = 0; j < 4; ++j) {
        const int f = tid + 256 * j;
        rowA[j] = f >> 3;
        sgA[j]  = (((f & 7) - (rowA[j] >> 1)) & 7) * 8;   // f16 elements
    }

    f32x4 acc[4][4] = {};

    for (int k0 = 0; k0 < INTER; k0 += BK) {
        #pragma unroll
        for (int j = 0; j < 4; ++j) {
            const int f = tid + 256 * j;
            const _Float16* pA = Hm + (size_t)(bm + rowA[j]) * INTER + k0 + sgA[j];
            const _Float16* pB = Wd + (size_t)(bn + rowA[j]) * INTER + k0 + sgA[j];
            __builtin_amdgcn_global_load_lds(
                (__attribute__((address_space(1))) void*)pA,
                (__attribute__((address_space(3))) void*)&As[f * 8], 16, 0, 0);
            __builtin_amdgcn_global_load_lds(
                (__attribute__((address_space(1))) void*)pB,
                (__attribute__((address_space(3))) void*)&Bs[f * 8], 16, 0, 0);
        }
        __syncthreads();

        #pragma unroll
        for (int ks = 0; ks < 2; ++ks) {
            const int q = ks * 4 + lq;
            f16x8 a[4];
            #pragma unroll
            for (int im = 0; im < 4; ++im)
                a[im] = *(const f16x8*)&As[swz8(wm + im * 16 + l15, q) * 8];
            #pragma unroll
            for (int jn = 0; jn < 4; ++jn) {
                f16x8 b = *(const f16x8*)&Bs[swz8(wn + jn * 16 + l15, q) * 8];
                #pragma unroll
                for (int im = 0; im < 4; ++im)
                    acc[im][jn] = __builtin_amdgcn_mfma_f32_16x16x32_f16(a[im], b, acc[im][jn], 0, 0, 0);
            }
        }
        __syncthreads();
    }

    #pragma unroll
    for (int jn = 0; jn < 4; ++jn) {
        const int col = bn + wn + jn * 16 + l15;
        const float sd = dsc[col];
        #pragma unroll
        for (int im = 0; im < 4; ++im) {
            const int rbase = bm + wm + im * 16 + lq * 4;
            #pragma unroll
            for (int r = 0; r < 4; ++r)
                out[(size_t)(rbase + r) * HIDDEN + col] = acc[im][jn][r] * sd;
        }
    }
}

// ---------------------------------------------------------------------------
// launch
// ---------------------------------------------------------------------------
extern "C" void kernel_launch(void* const* d_in, const int* in_sizes, int n_in,
                              void* d_out, int out_size, void* d_ws, size_t ws_size,
                              hipStream_t stream) {
    const float* x   = (const float*)d_in[0];
    const float* gw  = (const float*)d_in[1];
    const float* uw  = (const float*)d_in[2];
    const float* dw  = (const float*)d_in[3];
    const float* gsc = (const float*)d_in[4];
    const float* usc = (const float*)d_in[5];
    const float* dsc = (const float*)d_in[6];
    float* out = (float*)d_out;

    // workspace layout:
    //   Xq  i8  @          0 :  8,388,608
    //   Wg8 i8  @  8,388,608 : 11,534,336
    //   Wu8 i8  @ 19,922,944 : 11,534,336
    //   Wdh f16 @ 31,457,280 : 23,068,672
    //   Hm  f16 @ 54,525,952 : 46,137,344
    //   xs  f32 @100,663,296 :     16,384
    char* ws = (char*)d_ws;
    int8_t*   Xq  = (int8_t*)(ws);
    int8_t*   Wg8 = (int8_t*)(ws + 8388608ull);
    int8_t*   Wu8 = (int8_t*)(ws + 19922944ull);
    _Float16* Wdh = (_Float16*)(ws + 31457280ull);
    _Float16* Hm  = (_Float16*)(ws + 54525952ull);
    float*    xs  = (float*)(ws + 100663296ull);

    prepass<<<TOKENS + 2048, 256, 0, stream>>>(
        x, (const float4*)gw, (const float4*)uw, (const float4*)dw,
        Xq, xs, (int*)Wg8, (int*)Wu8, (f16x4*)Wdh);

    gemm_gateup<<<(INTER / 128) * (TOKENS / 128), 256, 0, stream>>>(
        Xq, Wg8, Wu8, xs, gsc, usc, Hm);
    gemm_down<<<(HIDDEN / 128) * (TOKENS / 128), 256, 0, stream>>>(
        Hm, Wdh, dsc, out);
}

// Round 7
// 375.375 us; speedup vs baseline: 1.1595x; 1.0348x over previous
//
#include <hip/hip_runtime.h>
#include <stdint.h>
#include <stddef.h>

#define HIDDEN 2048
#define INTER  5632
#define TOKENS 4096   // B*S = 2*2048
#define BK     64     // f16 K-tile (down GEMM)  -> 128B rows, 88 iters
#define BKI    128    // i8 K-tile (gateup GEMM) -> 128B rows, 16 iters

typedef __attribute__((ext_vector_type(8))) _Float16 f16x8;
typedef __attribute__((ext_vector_type(4))) _Float16 f16x4;
typedef __attribute__((ext_vector_type(4))) float    f32x4;
typedef __attribute__((ext_vector_type(4))) int      i32x4;

// 128B-row LDS swizzle, period-8 row rotation: global segment q of row r lives
// at slot r*8 + ((q + r) & 7).  ds_read_b128 conflict unit is an 8-lane phase
// (8 x 16B = all 32 banks, measured R5 vs R6): for fixed q, 8 consecutive rows
// map to 8 DISTINCT bank-quads -> conflict-free. (R6's row>>1 rotation gave
// only 4 quads/phase -> 2-way -> +4cyc/read, SQ_LDS_BANK_CONFLICT=1.15e7.)
__device__ __forceinline__ int swz8(int row, int q) {
    return row * 8 + ((q + row) & 7);
}

// ---------------------------------------------------------------------------
// fused prepass: blocks [0,TOKENS) quantize x per-token to i8;
// blocks [TOKENS, TOKENS+2048) grid-stride convert weights
// ---------------------------------------------------------------------------
__global__ __launch_bounds__(256)
void prepass(const float* __restrict__ x,
             const float4* __restrict__ gw, const float4* __restrict__ uw,
             const float4* __restrict__ dw,
             int8_t* __restrict__ xq, float* __restrict__ xs,
             int* __restrict__ go, int* __restrict__ uo,
             f16x4* __restrict__ dno) {
    const int tid = threadIdx.x;
    if (blockIdx.x < TOKENS) {
        const int t = blockIdx.x;
        const float4* row = (const float4*)(x + (size_t)t * HIDDEN);
        float4 v0 = row[tid * 2];
        float4 v1 = row[tid * 2 + 1];
        float m = fmaxf(fmaxf(fabsf(v0.x), fabsf(v0.y)), fmaxf(fabsf(v0.z), fabsf(v0.w)));
        m = fmaxf(m, fmaxf(fmaxf(fabsf(v1.x), fabsf(v1.y)), fmaxf(fabsf(v1.z), fabsf(v1.w))));
        #pragma unroll
        for (int off = 32; off; off >>= 1)
            m = fmaxf(m, __shfl_xor(m, off, 64));
        __shared__ float wmax[4];
        if ((tid & 63) == 0) wmax[tid >> 6] = m;
        __syncthreads();
        m = fmaxf(fmaxf(wmax[0], wmax[1]), fmaxf(wmax[2], wmax[3]));
        m = fmaxf(m, 1e-20f);
        if (tid == 0) xs[t] = m * (1.0f / 127.0f);
        const float inv = 127.0f / m;
        float vals[8] = {v0.x, v0.y, v0.z, v0.w, v1.x, v1.y, v1.z, v1.w};
        int b[8];
        #pragma unroll
        for (int i = 0; i < 8; ++i) b[i] = (int)rintf(vals[i] * inv);
        int lo = (b[0] & 255) | ((b[1] & 255) << 8) | ((b[2] & 255) << 16) | (b[3] << 24);
        int hi = (b[4] & 255) | ((b[5] & 255) << 8) | ((b[6] & 255) << 16) | (b[7] << 24);
        ((int2*)(xq + (size_t)t * HIDDEN))[tid] = make_int2(lo, hi);
        return;
    }
    const int NW4 = INTER * HIDDEN / 4;
    int i = (blockIdx.x - TOKENS) * blockDim.x + tid;
    const int stride = 2048 * blockDim.x;
    for (; i < 3 * NW4; i += stride) {
        if (i < 2 * NW4) {
            const bool is_g = i < NW4;
            const int j = is_g ? i : i - NW4;
            float4 f = is_g ? gw[j] : uw[j];
            int p = ((int)(signed char)(int)f.x & 255)
                  | (((int)(signed char)(int)f.y & 255) << 8)
                  | (((int)(signed char)(int)f.z & 255) << 16)
                  | (((int)(signed char)(int)f.w) << 24);
            if (is_g) go[j] = p; else uo[j] = p;
        } else {
            const int j = i - 2 * NW4;
            float4 f = dw[j];
            f16x4 o;
            o.x = (_Float16)f.x; o.y = (_Float16)f.y;
            o.z = (_Float16)f.z; o.w = (_Float16)f.w;
            dno[j] = o;
        }
    }
}

// ---------------------------------------------------------------------------
// GEMM1 fused (i8): H = silu(G*xs*gs) * (U*xs*us)  (fp16 out)
// 128x128 tile, BKI=128 (16 K-iters), LDS 48KB, band-swizzled grid.
// ---------------------------------------------------------------------------
__global__ __launch_bounds__(256, 2)
void gemm_gateup(const int8_t* __restrict__ Xq,
                 const int8_t* __restrict__ Wg,
                 const int8_t* __restrict__ Wu,
                 const float* __restrict__ xs,
                 const float* __restrict__ gs,
                 const float* __restrict__ us,
                 _Float16* __restrict__ Hm) {
    __shared__ int8_t As [128 * BKI];
    __shared__ int8_t Bgs[128 * BKI];
    __shared__ int8_t Bus[128 * BKI];

    const int pid   = blockIdx.x;          // 0..1407
    const int local = pid % (16 * 44);
    const int bm    = ((pid / (16 * 44)) * 16 + (local & 15)) * 128;
    const int bn    = (local >> 4) * 128;

    const int tid  = threadIdx.x;
    const int lane = tid & 63;
    const int wave = tid >> 6;
    const int wm   = (wave >> 1) * 64;
    const int wn   = (wave & 1) * 64;
    const int l15  = lane & 15;
    const int lq   = lane >> 4;

    // staging: 1024 16B-slots/tile, 256 threads x 4. slot f -> row f>>3,
    // fetches permuted global segment ((f&7) - row) & 7.
    int rowA[4], sgA[4];
    #pragma unroll
    for (int j = 0; j < 4; ++j) {
        const int f = tid + 256 * j;
        rowA[j] = f >> 3;
        sgA[j]  = (((f & 7) - rowA[j]) & 7) * 16;
    }

    i32x4 accg[4][4] = {};
    i32x4 accu[4][4] = {};

    for (int k0 = 0; k0 < HIDDEN; k0 += BKI) {
        #pragma unroll
        for (int j = 0; j < 4; ++j) {
            const int f = tid + 256 * j;
            const int8_t* pX = Xq + (size_t)(bm + rowA[j]) * HIDDEN + k0 + sgA[j];
            const int8_t* pG = Wg + (size_t)(bn + rowA[j]) * HIDDEN + k0 + sgA[j];
            const int8_t* pU = Wu + (size_t)(bn + rowA[j]) * HIDDEN + k0 + sgA[j];
            __builtin_amdgcn_global_load_lds(
                (__attribute__((address_space(1))) void*)pX,
                (__attribute__((address_space(3))) void*)&As[f * 16], 16, 0, 0);
            __builtin_amdgcn_global_load_lds(
                (__attribute__((address_space(1))) void*)pG,
                (__attribute__((address_space(3))) void*)&Bgs[f * 16], 16, 0, 0);
            __builtin_amdgcn_global_load_lds(
                (__attribute__((address_space(1))) void*)pU,
                (__attribute__((address_space(3))) void*)&Bus[f * 16], 16, 0, 0);
        }
        __syncthreads();

        #pragma unroll
        for (int ks = 0; ks < 2; ++ks) {
            const int q = ks * 4 + lq;     // segment for this MFMA k-step
            i32x4 a[4];
            #pragma unroll
            for (int im = 0; im < 4; ++im)
                a[im] = *(const i32x4*)&As[swz8(wm + im * 16 + l15, q) * 16];
            #pragma unroll
            for (int jn = 0; jn < 4; ++jn) {
                i32x4 bg = *(const i32x4*)&Bgs[swz8(wn + jn * 16 + l15, q) * 16];
                i32x4 bu = *(const i32x4*)&Bus[swz8(wn + jn * 16 + l15, q) * 16];
                #pragma unroll
                for (int im = 0; im < 4; ++im) {
                    accg[im][jn] = __builtin_amdgcn_mfma_i32_16x16x64_i8(a[im], bg, accg[im][jn], 0, 0, 0);
                    accu[im][jn] = __builtin_amdgcn_mfma_i32_16x16x64_i8(a[im], bu, accu[im][jn], 0, 0, 0);
                }
            }
        }
        __syncthreads();
    }

    #pragma unroll
    for (int jn = 0; jn < 4; ++jn) {
        const int col = bn + wn + jn * 16 + l15;
        const float sg = gs[col];
        const float su = us[col];
        #pragma unroll
        for (int im = 0; im < 4; ++im) {
            const int rbase = bm + wm + im * 16 + lq * 4;
            #pragma unroll
            for (int r = 0; r < 4; ++r) {
                const int row = rbase + r;
                const float st = xs[row];
                float g = (float)accg[im][jn][r] * st * sg;
                float u = (float)accu[im][jn][r] * st * su;
                float h = (g / (1.0f + __expf(-g))) * u;
                Hm[(size_t)row * INTER + col] = (_Float16)h;
            }
        }
    }
}

// ---------------------------------------------------------------------------
// GEMM2 (fp16): out = (H @ Wd^T) * down_s  (fp32 out)
// 128x128 tile, BK=64 (88 K-iters), LDS 32KB, band-swizzled grid.
// ---------------------------------------------------------------------------
__global__ __launch_bounds__(256, 2)
void gemm_down(const _Float16* __restrict__ Hm,
               const _Float16* __restrict__ Wd,
               const float* __restrict__ dsc,
               float* __restrict__ out) {
    __shared__ _Float16 As[128 * BK];
    __shared__ _Float16 Bs[128 * BK];

    const int pid = blockIdx.x;            // 0..511
    const int loc = pid & 255;
    const int bm  = ((pid >> 8) * 16 + (loc & 15)) * 128;
    const int bn  = (loc >> 4) * 128;

    const int tid  = threadIdx.x;
    const int lane = tid & 63;
    const int wave = tid >> 6;
    const int wm   = (wave >> 1) * 64;
    const int wn   = (wave & 1) * 64;
    const int l15  = lane & 15;
    const int lq   = lane >> 4;

    int rowA[4], sgA[4];
    #pragma unroll
    for (int j = 0; j < 4; ++j) {
        const int f = tid + 256 * j;
        rowA[j] = f >> 3;
        sgA[j]  = (((f & 7) - rowA[j]) & 7) * 8;   // f16 elements
    }

    f32x4 acc[4][4] = {};

    for (int k0 = 0; k0 < INTER; k0 += BK) {
        #pragma unroll
        for (int j = 0; j < 4; ++j) {
            const int f = tid + 256 * j;
            const _Float16* pA = Hm + (size_t)(bm + rowA[j]) * INTER + k0 + sgA[j];
            const _Float16* pB = Wd + (size_t)(bn + rowA[j]) * INTER + k0 + sgA[j];
            __builtin_amdgcn_global_load_lds(
                (__attribute__((address_space(1))) void*)pA,
                (__attribute__((address_space(3))) void*)&As[f * 8], 16, 0, 0);
            __builtin_amdgcn_global_load_lds(
                (__attribute__((address_space(1))) void*)pB,
                (__attribute__((address_space(3))) void*)&Bs[f * 8], 16, 0, 0);
        }
        __syncthreads();

        #pragma unroll
        for (int ks = 0; ks < 2; ++ks) {
            const int q = ks * 4 + lq;
            f16x8 a[4];
            #pragma unroll
            for (int im = 0; im < 4; ++im)
                a[im] = *(const f16x8*)&As[swz8(wm + im * 16 + l15, q) * 8];
            #pragma unroll
            for (int jn = 0; jn < 4; ++jn) {
                f16x8 b = *(const f16x8*)&Bs[swz8(wn + jn * 16 + l15, q) * 8];
                #pragma unroll
                for (int im = 0; im < 4; ++im)
                    acc[im][jn] = __builtin_amdgcn_mfma_f32_16x16x32_f16(a[im], b, acc[im][jn], 0, 0, 0);
            }
        }
        __syncthreads();
    }

    #pragma unroll
    for (int jn = 0; jn < 4; ++jn) {
        const int col = bn + wn + jn * 16 + l15;
        const float sd = dsc[col];
        #pragma unroll
        for (int im = 0; im < 4; ++im) {
            const int rbase = bm + wm + im * 16 + lq * 4;
            #pragma unroll
            for (int r = 0; r < 4; ++r)
                out[(size_t)(rbase + r) * HIDDEN + col] = acc[im][jn][r] * sd;
        }
    }
}

// ---------------------------------------------------------------------------
// launch
// ---------------------------------------------------------------------------
extern "C" void kernel_launch(void* const* d_in, const int* in_sizes, int n_in,
                              void* d_out, int out_size, void* d_ws, size_t ws_size,
                              hipStream_t stream) {
    const float* x   = (const float*)d_in[0];
    const float* gw  = (const float*)d_in[1];
    const float* uw  = (const float*)d_in[2];
    const float* dw  = (const float*)d_in[3];
    const float* gsc = (const float*)d_in[4];
    const float* usc = (const float*)d_in[5];
    const float* dsc = (const float*)d_in[6];
    float* out = (float*)d_out;

    // workspace layout:
    //   Xq  i8  @          0 :  8,388,608
    //   Wg8 i8  @  8,388,608 : 11,534,336
    //   Wu8 i8  @ 19,922,944 : 11,534,336
    //   Wdh f16 @ 31,457,280 : 23,068,672
    //   Hm  f16 @ 54,525,952 : 46,137,344
    //   xs  f32 @100,663,296 :     16,384
    char* ws = (char*)d_ws;
    int8_t*   Xq  = (int8_t*)(ws);
    int8_t*   Wg8 = (int8_t*)(ws + 8388608ull);
    int8_t*   Wu8 = (int8_t*)(ws + 19922944ull);
    _Float16* Wdh = (_Float16*)(ws + 31457280ull);
    _Float16* Hm  = (_Float16*)(ws + 54525952ull);
    float*    xs  = (float*)(ws + 100663296ull);

    prepass<<<TOKENS + 2048, 256, 0, stream>>>(
        x, (const float4*)gw, (const float4*)uw, (const float4*)dw,
        Xq, xs, (int*)Wg8, (int*)Wu8, (f16x4*)Wdh);

    gemm_gateup<<<(INTER / 128) * (TOKENS / 128), 256, 0, stream>>>(
        Xq, Wg8, Wu8, xs, gsc, usc, Hm);
    gemm_down<<<(HIDDEN / 128) * (TOKENS / 128), 256, 0, stream>>>(
        Hm, Wdh, dsc, out);
}